// Round 8
// baseline (3630.429 us; speedup 1.0000x reference)
//
#include <hip/hip_runtime.h>

#define Bb 32
#define Tt 2048
#define Dd 256
#define Hh 256
#define G3 768  // 3*H

typedef _Float16 h2_t __attribute__((ext_vector_type(2)));
typedef _Float16 f16x8 __attribute__((ext_vector_type(8)));
typedef float f32x4 __attribute__((ext_vector_type(4)));
union H2U { unsigned u; _Float16 h[2]; h2_t v; };
union V16 { uint4 u; f16x8 f; };

__device__ __forceinline__ float fdot2f(unsigned a, unsigned b, float c) {
#if __has_builtin(__builtin_amdgcn_fdot2)
    H2U ua, ub; ua.u = a; ub.u = b;
    return __builtin_amdgcn_fdot2(ua.v, ub.v, c, false);
#else
    H2U ua, ub; ua.u = a; ub.u = b;
    return c + (float)ua.h[0] * (float)ub.h[0] + (float)ua.h[1] * (float)ub.h[1];
#endif
}

__device__ __forceinline__ float frcpf(float x) {
#if __has_builtin(__builtin_amdgcn_rcpf)
    return __builtin_amdgcn_rcpf(x);
#else
    return 1.0f / x;
#endif
}
__device__ __forceinline__ float sigmoidf_(float s) { return frcpf(1.0f + __expf(-s)); }
__device__ __forceinline__ float tanhf_(float u) {
    float e = __expf(2.0f * u);
    return 1.0f - 2.0f * frcpf(e + 1.0f);
}
// scalar-in/scalar-out DPP helpers (never pass arrays -- R2 lesson)
__device__ __forceinline__ float dpp_xor1(float v) {
    return __int_as_float(__builtin_amdgcn_update_dpp(0, __float_as_int(v), 0xB1, 0xF, 0xF, true));
}
__device__ __forceinline__ float dpp_xor2(float v) {
    return __int_as_float(__builtin_amdgcn_update_dpp(0, __float_as_int(v), 0x4E, 0xF, 0xF, true));
}
// zero-instruction register-class pin: forces v into AGPRs at this point.
// (R7 lesson: do NOT hand-write the MFMA itself in asm -- the hazard
// recognizer can't pad an opaque INLINEASM; use the builtin and only pin
// the operand's class.)
__device__ __forceinline__ f16x8 agpr_pin(f16x8 v) {
    f16x8 r;
    asm("" : "=a"(r) : "0"(v));
    return r;
}

// ---------------------------------------------------------------------------
// k0: x fp32 -> f16 (into d_out scratch region)
// ---------------------------------------------------------------------------
__global__ void cvt_x_kernel(const float* __restrict__ x, _Float16* __restrict__ xo) {
    const size_t i = ((size_t)blockIdx.x * 256 + threadIdx.x) * 4;
    float4 v = *reinterpret_cast<const float4*>(x + i);
    H2U a, b;
    a.h[0] = (_Float16)v.x; a.h[1] = (_Float16)v.y;
    b.h[0] = (_Float16)v.z; b.h[1] = (_Float16)v.w;
    uint2 o; o.x = a.u; o.y = b.u;
    *reinterpret_cast<uint2*>(xo + i) = o;
}

// ---------------------------------------------------------------------------
// k1: WxT[n][k] f16 from Wx[k][n] fp32  (768 x 256)
// ---------------------------------------------------------------------------
__global__ void wxt_kernel(const float* __restrict__ Wx, _Float16* __restrict__ wxt) {
    const int o = blockIdx.x * 256 + threadIdx.x;  // o = n*128 + kp
    const int n = o >> 7, kp = o & 127;
    float f0 = Wx[(size_t)(2 * kp) * G3 + n];
    float f1 = Wx[(size_t)(2 * kp + 1) * G3 + n];
    H2U u; u.h[0] = (_Float16)f0; u.h[1] = (_Float16)f1;
    reinterpret_cast<unsigned*>(wxt)[o] = u.u;
}

// ---------------------------------------------------------------------------
// k2: xp = A(65536x256,f16) @ WxT^T + bias, f16 out. MFMA 16x16x32_f16.
// (unchanged -- ref-checked)
// ---------------------------------------------------------------------------
__global__ __launch_bounds__(256)
void gemm_xp_kernel(const _Float16* __restrict__ A, const _Float16* __restrict__ Bm,
                    const float* __restrict__ bias, _Float16* __restrict__ xp) {
    __shared__ _Float16 As[128][264];
    __shared__ _Float16 Bs[64][264];
    const int tid = threadIdx.x;
    const int m0 = (blockIdx.x / 12) * 128;
    const int n0 = (blockIdx.x % 12) * 64;

#pragma unroll
    for (int it = 0; it < 16; ++it) {
        int c = tid + it * 256, row = c >> 5, col = c & 31;
        uint4 v = *reinterpret_cast<const uint4*>(A + (size_t)(m0 + row) * 256 + col * 8);
        *reinterpret_cast<uint4*>(&As[row][col * 8]) = v;
    }
#pragma unroll
    for (int it = 0; it < 8; ++it) {
        int c = tid + it * 256, row = c >> 5, col = c & 31;
        uint4 v = *reinterpret_cast<const uint4*>(Bm + (size_t)(n0 + row) * 256 + col * 8);
        *reinterpret_cast<uint4*>(&Bs[row][col * 8]) = v;
    }
    __syncthreads();

    const int wave = tid >> 6, lane = tid & 63;
    const int wr = wave >> 1, wc = wave & 1;
    const int r16 = lane & 15, kg = lane >> 4;

    f32x4 acc[4][2];
#pragma unroll
    for (int mi = 0; mi < 4; ++mi)
#pragma unroll
        for (int ni = 0; ni < 2; ++ni) acc[mi][ni] = (f32x4){0.f, 0.f, 0.f, 0.f};

    float bv[2];
#pragma unroll
    for (int ni = 0; ni < 2; ++ni) bv[ni] = bias[n0 + wc * 32 + ni * 16 + r16];

#pragma unroll
    for (int kk = 0; kk < 8; ++kk) {
        f16x8 a[4], b2[2];
#pragma unroll
        for (int mi = 0; mi < 4; ++mi) {
            V16 t; t.u = *reinterpret_cast<const uint4*>(&As[wr * 64 + mi * 16 + r16][kk * 32 + kg * 8]);
            a[mi] = t.f;
        }
#pragma unroll
        for (int ni = 0; ni < 2; ++ni) {
            V16 t; t.u = *reinterpret_cast<const uint4*>(&Bs[wc * 32 + ni * 16 + r16][kk * 32 + kg * 8]);
            b2[ni] = t.f;
        }
#pragma unroll
        for (int mi = 0; mi < 4; ++mi)
#pragma unroll
            for (int ni = 0; ni < 2; ++ni)
                acc[mi][ni] = __builtin_amdgcn_mfma_f32_16x16x32_f16(a[mi], b2[ni], acc[mi][ni], 0, 0, 0);
    }

#pragma unroll
    for (int mi = 0; mi < 4; ++mi)
#pragma unroll
        for (int ni = 0; ni < 2; ++ni)
#pragma unroll
            for (int r = 0; r < 4; ++r) {
                int row = m0 + wr * 64 + mi * 16 + kg * 4 + r;
                int col = n0 + wc * 32 + ni * 16 + r16;
                xp[(size_t)row * G3 + col] = (_Float16)(acc[mi][ni][r] + bv[ni]);
            }
}

// ---------------------------------------------------------------------------
// k3: GRU scan -- VALU+MFMA two-pipe hybrid. 32 blocks x 256 threads
// (4 waves, 1/SIMD: allocator grants the full 256 arch VGPRs -- R5).
// Same structure as R7 EXCEPT the MFMA is the intrinsic (hazards handled)
// with B-fragments class-pinned to AGPRs at load time.
//  - VALU half: h-cols [32wv, 32wv+32): lane (s=lane>>2, q=lane&3) owns
//    cols {32wv+2s,+1} x 3 gates, k in [64q,64q+64): 192 weight u32 in
//    arch VGPRs (R6-verified math: quad-DPP reduce).
//  - MFMA half: h-cols [128+32wv, +32): 2 windows x 3 gates = 6 tiles x
//    8 K-frags; A = h broadcast (all 16 rows identical, R3-verified);
//    lanes 0..31 extract acc[0] and do gate math.
// h double-buffered in 1KB LDS; one lgkm-only barrier per step.
// ---------------------------------------------------------------------------
#define GKT(PR, KT)                                                                   \
  {                                                                                   \
    V16 af_; af_.u = *reinterpret_cast<const uint4*>(                                 \
        reinterpret_cast<const char*>(&hbuf[PR][0]) + (KT) * 64 + kg * 16);           \
    uint4 hv = *reinterpret_cast<const uint4*>(                                       \
        reinterpret_cast<const char*>(&hbuf[PR][0]) + q * 128 + (KT) * 16);           \
    az_a = __builtin_amdgcn_mfma_f32_16x16x32_f16(af_.f, bf[0][0][KT], az_a, 0, 0, 0); \
    vz0 = fdot2f(w[0][0][4 * (KT) + 0], hv.x, vz0);                                   \
    vz1 = fdot2f(w[0][1][4 * (KT) + 0], hv.x, vz1);                                   \
    vr0 = fdot2f(w[1][0][4 * (KT) + 0], hv.x, vr0);                                   \
    vr1 = fdot2f(w[1][1][4 * (KT) + 0], hv.x, vr1);                                   \
    az_b = __builtin_amdgcn_mfma_f32_16x16x32_f16(af_.f, bf[0][1][KT], az_b, 0, 0, 0); \
    vn0 = fdot2f(w[2][0][4 * (KT) + 0], hv.x, vn0);                                   \
    vn1 = fdot2f(w[2][1][4 * (KT) + 0], hv.x, vn1);                                   \
    vz0 = fdot2f(w[0][0][4 * (KT) + 1], hv.y, vz0);                                   \
    vz1 = fdot2f(w[0][1][4 * (KT) + 1], hv.y, vz1);                                   \
    ar_a = __builtin_amdgcn_mfma_f32_16x16x32_f16(af_.f, bf[1][0][KT], ar_a, 0, 0, 0); \
    vr0 = fdot2f(w[1][0][4 * (KT) + 1], hv.y, vr0);                                   \
    vr1 = fdot2f(w[1][1][4 * (KT) + 1], hv.y, vr1);                                   \
    vn0 = fdot2f(w[2][0][4 * (KT) + 1], hv.y, vn0);                                   \
    vn1 = fdot2f(w[2][1][4 * (KT) + 1], hv.y, vn1);                                   \
    ar_b = __builtin_amdgcn_mfma_f32_16x16x32_f16(af_.f, bf[1][1][KT], ar_b, 0, 0, 0); \
    vz0 = fdot2f(w[0][0][4 * (KT) + 2], hv.z, vz0);                                   \
    vz1 = fdot2f(w[0][1][4 * (KT) + 2], hv.z, vz1);                                   \
    vr0 = fdot2f(w[1][0][4 * (KT) + 2], hv.z, vr0);                                   \
    vr1 = fdot2f(w[1][1][4 * (KT) + 2], hv.z, vr1);                                   \
    an_a = __builtin_amdgcn_mfma_f32_16x16x32_f16(af_.f, bf[2][0][KT], an_a, 0, 0, 0); \
    vn0 = fdot2f(w[2][0][4 * (KT) + 2], hv.z, vn0);                                   \
    vn1 = fdot2f(w[2][1][4 * (KT) + 2], hv.z, vn1);                                   \
    vz0 = fdot2f(w[0][0][4 * (KT) + 3], hv.w, vz0);                                   \
    vz1 = fdot2f(w[0][1][4 * (KT) + 3], hv.w, vz1);                                   \
    an_b = __builtin_amdgcn_mfma_f32_16x16x32_f16(af_.f, bf[2][1][KT], an_b, 0, 0, 0); \
    vr0 = fdot2f(w[1][0][4 * (KT) + 3], hv.w, vr0);                                   \
    vr1 = fdot2f(w[1][1][4 * (KT) + 3], hv.w, vr1);                                   \
    vn0 = fdot2f(w[2][0][4 * (KT) + 3], hv.w, vn0);                                   \
    vn1 = fdot2f(w[2][1][4 * (KT) + 3], hv.w, vn1);                                   \
  }

#define GSTEP(PR, PW, T)                                                              \
  {                                                                                   \
    /* x-proj loads for THIS step; consumed ~900 cyc later at gate time */            \
    unsigned xvz = 0u, xvr = 0u, xvn = 0u;                                            \
    _Float16 xmz = (_Float16)0.f, xmr = (_Float16)0.f, xmn = (_Float16)0.f;           \
    if (q == 0) {                                                                     \
      const _Float16* xt = xpv + (size_t)(T) * G3;                                    \
      xvz = *reinterpret_cast<const unsigned*>(xt);                                   \
      xvr = *reinterpret_cast<const unsigned*>(xt + Hh);                              \
      xvn = *reinterpret_cast<const unsigned*>(xt + 2 * Hh);                          \
    }                                                                                 \
    if (lane < 32) {                                                                  \
      const _Float16* xt = xpm + (size_t)(T) * G3;                                    \
      xmz = xt[0]; xmr = xt[Hh]; xmn = xt[2 * Hh];                                    \
    }                                                                                 \
    f32x4 az_a = {0.f, 0.f, 0.f, 0.f}, az_b = {0.f, 0.f, 0.f, 0.f};                   \
    f32x4 ar_a = {0.f, 0.f, 0.f, 0.f}, ar_b = {0.f, 0.f, 0.f, 0.f};                   \
    f32x4 an_a = {0.f, 0.f, 0.f, 0.f}, an_b = {0.f, 0.f, 0.f, 0.f};                   \
    float vz0 = 0.f, vz1 = 0.f, vr0 = 0.f, vr1 = 0.f, vn0 = 0.f, vn1 = 0.f;           \
    GKT(PR, 0) GKT(PR, 1) GKT(PR, 2) GKT(PR, 3)                                       \
    GKT(PR, 4) GKT(PR, 5) GKT(PR, 6) GKT(PR, 7)                                       \
    vz0 += dpp_xor1(vz0); vz1 += dpp_xor1(vz1);                                       \
    vr0 += dpp_xor1(vr0); vr1 += dpp_xor1(vr1);                                       \
    vn0 += dpp_xor1(vn0); vn1 += dpp_xor1(vn1);                                       \
    vz0 += dpp_xor2(vz0); vz1 += dpp_xor2(vz1);                                       \
    vr0 += dpp_xor2(vr0); vr1 += dpp_xor2(vr1);                                       \
    vn0 += dpp_xor2(vn0); vn1 += dpp_xor2(vn1);                                       \
    if (q == 0) {                                                                     \
      H2U uz, ur, un; uz.u = xvz; ur.u = xvr; un.u = xvn;                             \
      float z0 = sigmoidf_((float)uz.h[0] + vz0);                                     \
      float r0 = sigmoidf_((float)ur.h[0] + vr0);                                     \
      float n0 = tanhf_((float)un.h[0] + r0 * vn0);                                   \
      float hn0 = z0 * hv_prev0 + (1.0f - z0) * n0;                                   \
      float z1 = sigmoidf_((float)uz.h[1] + vz1);                                     \
      float r1 = sigmoidf_((float)ur.h[1] + vr1);                                     \
      float n1 = tanhf_((float)un.h[1] + r1 * vn1);                                   \
      float hn1 = z1 * hv_prev1 + (1.0f - z1) * n1;                                   \
      hv_prev0 = hn0; hv_prev1 = hn1;                                                 \
      H2U hp; hp.h[0] = (_Float16)hn0; hp.h[1] = (_Float16)hn1;                       \
      hbuf[PW][16 * wv + s] = hp.u;                                                   \
      float2 yv; yv.x = hn0; yv.y = hn1;                                              \
      *reinterpret_cast<float2*>(ybv + (size_t)(T) * Hh) = yv;                        \
    }                                                                                 \
    if (lane < 32) {                                                                  \
      float mz = (lane & 16) ? az_b[0] : az_a[0];                                     \
      float mr = (lane & 16) ? ar_b[0] : ar_a[0];                                     \
      float mn = (lane & 16) ? an_b[0] : an_a[0];                                     \
      float zg = sigmoidf_((float)xmz + mz);                                          \
      float rg = sigmoidf_((float)xmr + mr);                                          \
      float ng = tanhf_((float)xmn + rg * mn);                                        \
      float hm = zg * hm_prev + (1.0f - zg) * ng;                                     \
      hm_prev = hm;                                                                   \
      reinterpret_cast<_Float16*>(&hbuf[PW][0])[jm] = (_Float16)hm;                   \
      ybm[(size_t)(T) * Hh] = hm;                                                     \
    }                                                                                 \
    __builtin_amdgcn_sched_barrier(0);                                                \
    asm volatile("s_waitcnt lgkmcnt(0)" ::: "memory");                                \
    __builtin_amdgcn_s_barrier();                                                     \
    __builtin_amdgcn_sched_barrier(0);                                                \
  }

__global__ __launch_bounds__(256)
__attribute__((amdgpu_waves_per_eu(1, 1)))
void gru_scan_kernel(const _Float16* __restrict__ xp, const float* __restrict__ Wh,
                     float* __restrict__ y) {
    __shared__ unsigned hbuf[2][128];  // 2 x 256 f16, linear

    const int tid = threadIdx.x;
    const int b = blockIdx.x;
    const int wv = tid >> 6, lane = tid & 63;
    const int q = lane & 3, s = lane >> 2;
    const int r16 = lane & 15, kg = lane >> 4;

    // --- VALU weights: cols {32wv+2s, +1} x 3 gates, k in [64q, 64q+64) ---
    unsigned w[3][2][32];
#pragma unroll
    for (int g = 0; g < 3; ++g) {
        const int c0 = g * Hh + 32 * wv + 2 * s;
#pragma unroll
        for (int kp = 0; kp < 32; ++kp) {
            const int k = 64 * q + 2 * kp;
            float2 f0 = *reinterpret_cast<const float2*>(Wh + (size_t)k * G3 + c0);
            float2 f1 = *reinterpret_cast<const float2*>(Wh + (size_t)(k + 1) * G3 + c0);
            H2U p0, p1;
            p0.h[0] = (_Float16)f0.x; p0.h[1] = (_Float16)f1.x;
            p1.h[0] = (_Float16)f0.y; p1.h[1] = (_Float16)f1.y;
            w[g][0][kp] = p0.u;
            w[g][1][kp] = p1.u;
        }
    }

    // --- MFMA B-fragments: col = g*256 + 128+32wv+16w2+r16, k = 32kt+8kg+j ---
    // agpr_pin forces AGPR residency at init (zero loop-time moves; the
    // builtin's operands are av-class so AGPR reads are native).
    f16x8 bf[3][2][8];
#pragma unroll
    for (int g = 0; g < 3; ++g)
#pragma unroll
        for (int w2 = 0; w2 < 2; ++w2)
#pragma unroll
            for (int kt = 0; kt < 8; ++kt) {
                V16 t;
#pragma unroll
                for (int j = 0; j < 8; ++j) {
                    const int k = 32 * kt + 8 * kg + j;
                    t.f[j] = (_Float16)Wh[(size_t)k * G3 + g * Hh + 128 + 32 * wv + 16 * w2 + r16];
                }
                bf[g][w2][kt] = agpr_pin(t.f);
            }

    if (tid < 128) hbuf[0][tid] = 0u;  // h0 = 0
    float hv_prev0 = 0.f, hv_prev1 = 0.f, hm_prev = 0.f;

    const int jv = 32 * wv + 2 * s;              // VALU cols (q==0 lanes)
    const int jm = 128 + 32 * wv + (lane & 31);  // MFMA col (lanes < 32)
    const _Float16* xpv = xp + (size_t)b * Tt * G3 + jv;
    const _Float16* xpm = xp + (size_t)b * Tt * G3 + jm;
    float* ybv = y + (size_t)b * Tt * Hh + jv;
    float* ybm = y + (size_t)b * Tt * Hh + jm;

    __syncthreads();  // one-time full barrier (drains weight loads too)

#pragma unroll 1
    for (int t = 0; t < Tt; t += 2) {
        GSTEP(0, 1, t);
        GSTEP(1, 0, t + 1);
    }
}

extern "C" void kernel_launch(void* const* d_in, const int* in_sizes, int n_in,
                              void* d_out, int out_size, void* d_ws, size_t ws_size,
                              hipStream_t stream) {
    (void)in_sizes; (void)n_in; (void)out_size; (void)ws_size;
    const float* x    = (const float*)d_in[0];
    const float* Wx   = (const float*)d_in[1];
    const float* Wh   = (const float*)d_in[2];
    const float* bias = (const float*)d_in[3];
    float* y = (float*)d_out;

    _Float16* xp   = (_Float16*)d_ws;                                // 96 MB
    _Float16* xf16 = (_Float16*)d_out;                               // 33.5 MB scratch in d_out
    _Float16* wxt  = (_Float16*)((char*)d_out + (size_t)33554432);   // 384 KB, after xf16

    cvt_x_kernel<<<dim3(16384), dim3(256), 0, stream>>>(x, xf16);
    wxt_kernel<<<dim3(384), dim3(256), 0, stream>>>(Wx, wxt);
    gemm_xp_kernel<<<dim3(6144), dim3(256), 0, stream>>>(xf16, wxt, bias, xp);
    // scan reads only ws, writes all of d_out (overwriting the scratch regions)
    gru_scan_kernel<<<dim3(Bb), dim3(256), 0, stream>>>(xp, Wh, y);
}

// Round 9
// 2900.365 us; speedup vs baseline: 1.2517x; 1.2517x over previous
//
#include <hip/hip_runtime.h>

#define Bb 32
#define Tt 2048
#define Dd 256
#define Hh 256
#define G3 768  // 3*H

typedef _Float16 h2_t __attribute__((ext_vector_type(2)));
typedef _Float16 f16x8 __attribute__((ext_vector_type(8)));
typedef float f32x4 __attribute__((ext_vector_type(4)));
union H2U { unsigned u; _Float16 h[2]; h2_t v; };
union V16 { uint4 u; f16x8 f; };

__device__ __forceinline__ float fdot2f(unsigned a, unsigned b, float c) {
#if __has_builtin(__builtin_amdgcn_fdot2)
    H2U ua, ub; ua.u = a; ub.u = b;
    return __builtin_amdgcn_fdot2(ua.v, ub.v, c, false);
#else
    H2U ua, ub; ua.u = a; ub.u = b;
    return c + (float)ua.h[0] * (float)ub.h[0] + (float)ua.h[1] * (float)ub.h[1];
#endif
}

__device__ __forceinline__ float frcpf(float x) {
#if __has_builtin(__builtin_amdgcn_rcpf)
    return __builtin_amdgcn_rcpf(x);
#else
    return 1.0f / x;
#endif
}
__device__ __forceinline__ float sigmoidf_(float s) { return frcpf(1.0f + __expf(-s)); }
__device__ __forceinline__ float tanhf_(float u) {
    float e = __expf(2.0f * u);
    return 1.0f - 2.0f * frcpf(e + 1.0f);
}
// cross-kg reduction: xor-16 (ds_swizzle BitMode, ISA-doc pattern) then
// xor-32 (__shfl_xor, compiler picks the correct cross-half instruction).
// scalar-in/scalar-out (R2 lesson: never pass arrays by pointer).
__device__ __forceinline__ float red4(float v) {
    v += __int_as_float(__builtin_amdgcn_ds_swizzle(__float_as_int(v), 0x401F)); // lane ^= 16
    v += __shfl_xor(v, 32, 64);                                                  // lane ^= 32
    return v;
}
// zero-instruction register-class pin -> AGPR (R7/R8 lesson: builtin MFMA
// for hazard handling; pin only the operand's class).
__device__ __forceinline__ f16x8 agpr_pin(f16x8 v) {
    f16x8 r;
    asm("" : "=a"(r) : "0"(v));
    return r;
}

// ---------------------------------------------------------------------------
// k0: x fp32 -> f16 (into d_out scratch region)
// ---------------------------------------------------------------------------
__global__ void cvt_x_kernel(const float* __restrict__ x, _Float16* __restrict__ xo) {
    const size_t i = ((size_t)blockIdx.x * 256 + threadIdx.x) * 4;
    float4 v = *reinterpret_cast<const float4*>(x + i);
    H2U a, b;
    a.h[0] = (_Float16)v.x; a.h[1] = (_Float16)v.y;
    b.h[0] = (_Float16)v.z; b.h[1] = (_Float16)v.w;
    uint2 o; o.x = a.u; o.y = b.u;
    *reinterpret_cast<uint2*>(xo + i) = o;
}

// ---------------------------------------------------------------------------
// k1: WxT[n][k] f16 from Wx[k][n] fp32  (768 x 256)
// ---------------------------------------------------------------------------
__global__ void wxt_kernel(const float* __restrict__ Wx, _Float16* __restrict__ wxt) {
    const int o = blockIdx.x * 256 + threadIdx.x;  // o = n*128 + kp
    const int n = o >> 7, kp = o & 127;
    float f0 = Wx[(size_t)(2 * kp) * G3 + n];
    float f1 = Wx[(size_t)(2 * kp + 1) * G3 + n];
    H2U u; u.h[0] = (_Float16)f0; u.h[1] = (_Float16)f1;
    reinterpret_cast<unsigned*>(wxt)[o] = u.u;
}

// ---------------------------------------------------------------------------
// k2: xp = A(65536x256,f16) @ WxT^T + bias, f16 out. MFMA 16x16x32_f16.
// (unchanged -- ref-checked)
// ---------------------------------------------------------------------------
__global__ __launch_bounds__(256)
void gemm_xp_kernel(const _Float16* __restrict__ A, const _Float16* __restrict__ Bm,
                    const float* __restrict__ bias, _Float16* __restrict__ xp) {
    __shared__ _Float16 As[128][264];
    __shared__ _Float16 Bs[64][264];
    const int tid = threadIdx.x;
    const int m0 = (blockIdx.x / 12) * 128;
    const int n0 = (blockIdx.x % 12) * 64;

#pragma unroll
    for (int it = 0; it < 16; ++it) {
        int c = tid + it * 256, row = c >> 5, col = c & 31;
        uint4 v = *reinterpret_cast<const uint4*>(A + (size_t)(m0 + row) * 256 + col * 8);
        *reinterpret_cast<uint4*>(&As[row][col * 8]) = v;
    }
#pragma unroll
    for (int it = 0; it < 8; ++it) {
        int c = tid + it * 256, row = c >> 5, col = c & 31;
        uint4 v = *reinterpret_cast<const uint4*>(Bm + (size_t)(n0 + row) * 256 + col * 8);
        *reinterpret_cast<uint4*>(&Bs[row][col * 8]) = v;
    }
    __syncthreads();

    const int wave = tid >> 6, lane = tid & 63;
    const int wr = wave >> 1, wc = wave & 1;
    const int r16 = lane & 15, kg = lane >> 4;

    f32x4 acc[4][2];
#pragma unroll
    for (int mi = 0; mi < 4; ++mi)
#pragma unroll
        for (int ni = 0; ni < 2; ++ni) acc[mi][ni] = (f32x4){0.f, 0.f, 0.f, 0.f};

    float bv[2];
#pragma unroll
    for (int ni = 0; ni < 2; ++ni) bv[ni] = bias[n0 + wc * 32 + ni * 16 + r16];

#pragma unroll
    for (int kk = 0; kk < 8; ++kk) {
        f16x8 a[4], b2[2];
#pragma unroll
        for (int mi = 0; mi < 4; ++mi) {
            V16 t; t.u = *reinterpret_cast<const uint4*>(&As[wr * 64 + mi * 16 + r16][kk * 32 + kg * 8]);
            a[mi] = t.f;
        }
#pragma unroll
        for (int ni = 0; ni < 2; ++ni) {
            V16 t; t.u = *reinterpret_cast<const uint4*>(&Bs[wc * 32 + ni * 16 + r16][kk * 32 + kg * 8]);
            b2[ni] = t.f;
        }
#pragma unroll
        for (int mi = 0; mi < 4; ++mi)
#pragma unroll
            for (int ni = 0; ni < 2; ++ni)
                acc[mi][ni] = __builtin_amdgcn_mfma_f32_16x16x32_f16(a[mi], b2[ni], acc[mi][ni], 0, 0, 0);
    }

#pragma unroll
    for (int mi = 0; mi < 4; ++mi)
#pragma unroll
        for (int ni = 0; ni < 2; ++ni)
#pragma unroll
            for (int r = 0; r < 4; ++r) {
                int row = m0 + wr * 64 + mi * 16 + kg * 4 + r;
                int col = n0 + wc * 32 + ni * 16 + r16;
                xp[(size_t)row * G3 + col] = (_Float16)(acc[mi][ni][r] + bv[ni]);
            }
}

// ---------------------------------------------------------------------------
// k3: GRU scan -- VALU+MFMA hybrid, UNIFIED h-read. 32 blocks x 256 threads
// (1 wave/SIMD: R5/R8-proven full-256-VGPR regime; weights fully resident,
// FETCH confirms). R8 was latency-bound (4150 cyc/step, both pipes <40%):
// 16 read-then-use ds_read chains + 4-way hv bank conflicts, no second wave
// to hide them. Fix:
//  * VALU k-split re-keyed to kg = lane>>4 == the MFMA A-fragment grouping,
//    so the SAME 8 broadcast ds_read_b128 (rolling 4-deep, issued ahead of
//    use) feed both pipes. Banks disjoint per 16-lane group -> 0 conflicts.
//  * cross-kg reduce = ds_swizzle xor-16 + __shfl_xor 32 (red4).
//  * gate math unconditional (VALU is wave-wide; branches only on stores).
// Per wave: VALU cols [32wv,+32) (lane s16 owns 2), MFMA cols [128+32wv,+32)
// (6 tiles x 8 K-frags, B in AGPRs via agpr_pin). 192 VGPR weights + 216 AGPR.
// ---------------------------------------------------------------------------
#define DOT6(HU, KP)                                                                  \
    vz0 = fdot2f(w[0][0][KP], HU, vz0); vz1 = fdot2f(w[0][1][KP], HU, vz1);           \
    vr0 = fdot2f(w[1][0][KP], HU, vr0); vr1 = fdot2f(w[1][1][KP], HU, vr1);           \
    vn0 = fdot2f(w[2][0][KP], HU, vn0); vn1 = fdot2f(w[2][1][KP], HU, vn1);

#define GKT(KT, AF)                                                                   \
  {                                                                                   \
    az_a = __builtin_amdgcn_mfma_f32_16x16x32_f16(AF.f, bf[0][0][KT], az_a, 0, 0, 0); \
    DOT6(AF.u.x, 4 * (KT) + 0)                                                        \
    az_b = __builtin_amdgcn_mfma_f32_16x16x32_f16(AF.f, bf[0][1][KT], az_b, 0, 0, 0); \
    DOT6(AF.u.y, 4 * (KT) + 1)                                                        \
    ar_a = __builtin_amdgcn_mfma_f32_16x16x32_f16(AF.f, bf[1][0][KT], ar_a, 0, 0, 0); \
    DOT6(AF.u.z, 4 * (KT) + 2)                                                        \
    ar_b = __builtin_amdgcn_mfma_f32_16x16x32_f16(AF.f, bf[1][1][KT], ar_b, 0, 0, 0); \
    DOT6(AF.u.w, 4 * (KT) + 3)                                                        \
    an_a = __builtin_amdgcn_mfma_f32_16x16x32_f16(AF.f, bf[2][0][KT], an_a, 0, 0, 0); \
    an_b = __builtin_amdgcn_mfma_f32_16x16x32_f16(AF.f, bf[2][1][KT], an_b, 0, 0, 0); \
  }

#define GSTEP(PR, PW, T)                                                              \
  {                                                                                   \
    /* x-proj loads (all lanes; consumed at gate time ~1000 cyc later) */             \
    const _Float16* xt = xq + (size_t)(T) * G3;                                       \
    const unsigned xzp = *reinterpret_cast<const unsigned*>(xt);                      \
    const unsigned xrp = *reinterpret_cast<const unsigned*>(xt + Hh);                 \
    const unsigned xnp = *reinterpret_cast<const unsigned*>(xt + 2 * Hh);             \
    const _Float16* xs = xm + (size_t)(T) * G3;                                       \
    const _Float16 xmz = xs[0], xmr = xs[Hh], xmn = xs[2 * Hh];                       \
    f32x4 az_a = {0.f, 0.f, 0.f, 0.f}, az_b = {0.f, 0.f, 0.f, 0.f};                   \
    f32x4 ar_a = {0.f, 0.f, 0.f, 0.f}, ar_b = {0.f, 0.f, 0.f, 0.f};                   \
    f32x4 an_a = {0.f, 0.f, 0.f, 0.f}, an_b = {0.f, 0.f, 0.f, 0.f};                   \
    float vz0 = 0.f, vz1 = 0.f, vr0 = 0.f, vr1 = 0.f, vn0 = 0.f, vn1 = 0.f;           \
    const char* hb_ = reinterpret_cast<const char*>(&hbuf[PR][0]) + kg * 16;          \
    V16 a0, a1, a2, a3;                                                               \
    a0.u = *reinterpret_cast<const uint4*>(hb_ + 0);                                  \
    a1.u = *reinterpret_cast<const uint4*>(hb_ + 64);                                 \
    a2.u = *reinterpret_cast<const uint4*>(hb_ + 128);                                \
    a3.u = *reinterpret_cast<const uint4*>(hb_ + 192);                                \
    GKT(0, a0) GKT(1, a1)                                                             \
    a0.u = *reinterpret_cast<const uint4*>(hb_ + 256);                                \
    a1.u = *reinterpret_cast<const uint4*>(hb_ + 320);                                \
    GKT(2, a2) GKT(3, a3)                                                             \
    a2.u = *reinterpret_cast<const uint4*>(hb_ + 384);                                \
    a3.u = *reinterpret_cast<const uint4*>(hb_ + 448);                                \
    GKT(4, a0) GKT(5, a1) GKT(6, a2) GKT(7, a3)                                       \
    /* cross-kg reduce: all lanes end with full-k sums */                             \
    vz0 = red4(vz0); vz1 = red4(vz1);                                                 \
    vr0 = red4(vr0); vr1 = red4(vr1);                                                 \
    vn0 = red4(vn0); vn1 = red4(vn1);                                                 \
    /* VALU gates (wave-wide; all kg copies identical) */                             \
    H2U uz, ur, un; uz.u = xzp; ur.u = xrp; un.u = xnp;                               \
    const float z0 = sigmoidf_((float)uz.h[0] + vz0);                                 \
    const float r0 = sigmoidf_((float)ur.h[0] + vr0);                                 \
    const float n0 = tanhf_((float)un.h[0] + r0 * vn0);                               \
    const float hn0 = z0 * hv_prev0 + (1.0f - z0) * n0;                               \
    const float z1 = sigmoidf_((float)uz.h[1] + vz1);                                 \
    const float r1 = sigmoidf_((float)ur.h[1] + vr1);                                 \
    const float n1 = tanhf_((float)un.h[1] + r1 * vn1);                               \
    const float hn1 = z1 * hv_prev1 + (1.0f - z1) * n1;                               \
    hv_prev0 = hn0; hv_prev1 = hn1;                                                   \
    if (lane < 16) {                                                                  \
      H2U hp; hp.h[0] = (_Float16)hn0; hp.h[1] = (_Float16)hn1;                       \
      hbuf[PW][16 * wv + s16] = hp.u;                                                 \
      float2 yv; yv.x = hn0; yv.y = hn1;                                              \
      *reinterpret_cast<float2*>(ybv + (size_t)(T) * Hh) = yv;                        \
    }                                                                                 \
    /* MFMA gates (lanes 32-63 duplicate 0-31; consistent) */                         \
    const float mz = (lane & 16) ? az_b[0] : az_a[0];                                 \
    const float mr = (lane & 16) ? ar_b[0] : ar_a[0];                                 \
    const float mn = (lane & 16) ? an_b[0] : an_a[0];                                 \
    const float zg = sigmoidf_((float)xmz + mz);                                      \
    const float rg = sigmoidf_((float)xmr + mr);                                      \
    const float ng = tanhf_((float)xmn + rg * mn);                                    \
    const float hm = zg * hm_prev + (1.0f - zg) * ng;                                 \
    hm_prev = hm;                                                                     \
    if (lane < 32) {                                                                  \
      reinterpret_cast<_Float16*>(&hbuf[PW][0])[jm] = (_Float16)hm;                   \
      ybm[(size_t)(T) * Hh] = hm;                                                     \
    }                                                                                 \
    __builtin_amdgcn_sched_barrier(0);                                                \
    asm volatile("s_waitcnt lgkmcnt(0)" ::: "memory");                                \
    __builtin_amdgcn_s_barrier();                                                     \
    __builtin_amdgcn_sched_barrier(0);                                                \
  }

__global__ __launch_bounds__(256)
__attribute__((amdgpu_waves_per_eu(1, 1)))
void gru_scan_kernel(const _Float16* __restrict__ xp, const float* __restrict__ Wh,
                     float* __restrict__ y) {
    __shared__ unsigned hbuf[2][128];  // 2 x 256 f16, linear (reads are broadcast: 0 conflicts)

    const int tid = threadIdx.x;
    const int b = blockIdx.x;
    const int wv = tid >> 6, lane = tid & 63;
    const int s16 = lane & 15, kg = lane >> 4;

    // --- VALU weights: cols {32wv+2s16, +1} x 3 gates, k-set == A-frag set:
    //     k = 32*kt + 8*kg + 2*i + {0,1}  -> w[g][c][4*kt+i]  (192 u32) ---
    unsigned w[3][2][32];
#pragma unroll
    for (int g = 0; g < 3; ++g) {
        const int c0 = g * Hh + 32 * wv + 2 * s16;
#pragma unroll
        for (int kt = 0; kt < 8; ++kt)
#pragma unroll
            for (int i = 0; i < 4; ++i) {
                const int k = 32 * kt + 8 * kg + 2 * i;
                float2 f0 = *reinterpret_cast<const float2*>(Wh + (size_t)k * G3 + c0);
                float2 f1 = *reinterpret_cast<const float2*>(Wh + (size_t)(k + 1) * G3 + c0);
                H2U p0, p1;
                p0.h[0] = (_Float16)f0.x; p0.h[1] = (_Float16)f1.x;
                p1.h[0] = (_Float16)f0.y; p1.h[1] = (_Float16)f1.y;
                w[g][0][4 * kt + i] = p0.u;
                w[g][1][4 * kt + i] = p1.u;
            }
    }

    // --- MFMA B-fragments (AGPR-pinned): col = g*256 + 128+32wv+16w2+(lane&15),
    //     k = 32kt + 8kg + j ---
    f16x8 bf[3][2][8];
#pragma unroll
    for (int g = 0; g < 3; ++g)
#pragma unroll
        for (int w2 = 0; w2 < 2; ++w2)
#pragma unroll
            for (int kt = 0; kt < 8; ++kt) {
                V16 t;
#pragma unroll
                for (int j = 0; j < 8; ++j) {
                    const int k = 32 * kt + 8 * kg + j;
                    t.f[j] = (_Float16)Wh[(size_t)k * G3 + g * Hh + 128 + 32 * wv + 16 * w2 + s16];
                }
                bf[g][w2][kt] = agpr_pin(t.f);
            }

    if (tid < 128) hbuf[0][tid] = 0u;  // h0 = 0
    float hv_prev0 = 0.f, hv_prev1 = 0.f, hm_prev = 0.f;

    const int jv = 32 * wv + 2 * s16;            // VALU col pair base
    const int jm = 128 + 32 * wv + (lane & 31);  // MFMA col (lanes < 32 store)
    const _Float16* xq = xp + (size_t)b * Tt * G3 + jv;
    const _Float16* xm = xp + (size_t)b * Tt * G3 + jm;
    float* ybv = y + (size_t)b * Tt * Hh + jv;
    float* ybm = y + (size_t)b * Tt * Hh + jm;

    __syncthreads();  // one-time full barrier (drains weight loads too)

#pragma unroll 1
    for (int t = 0; t < Tt; t += 2) {
        GSTEP(0, 1, t);
        GSTEP(1, 0, t + 1);
    }
}

extern "C" void kernel_launch(void* const* d_in, const int* in_sizes, int n_in,
                              void* d_out, int out_size, void* d_ws, size_t ws_size,
                              hipStream_t stream) {
    (void)in_sizes; (void)n_in; (void)out_size; (void)ws_size;
    const float* x    = (const float*)d_in[0];
    const float* Wx   = (const float*)d_in[1];
    const float* Wh   = (const float*)d_in[2];
    const float* bias = (const float*)d_in[3];
    float* y = (float*)d_out;

    _Float16* xp   = (_Float16*)d_ws;                                // 96 MB
    _Float16* xf16 = (_Float16*)d_out;                               // 33.5 MB scratch in d_out
    _Float16* wxt  = (_Float16*)((char*)d_out + (size_t)33554432);   // 384 KB, after xf16

    cvt_x_kernel<<<dim3(16384), dim3(256), 0, stream>>>(x, xf16);
    wxt_kernel<<<dim3(384), dim3(256), 0, stream>>>(Wx, wxt);
    gemm_xp_kernel<<<dim3(6144), dim3(256), 0, stream>>>(xf16, wxt, bias, xp);
    // scan reads only ws, writes all of d_out (overwriting the scratch regions)
    gru_scan_kernel<<<dim3(Bb), dim3(256), 0, stream>>>(xp, Wh, y);
}

// Round 10
// 2726.815 us; speedup vs baseline: 1.3314x; 1.0636x over previous
//
#include <hip/hip_runtime.h>

#define Bb 32
#define Tt 2048
#define Dd 256
#define Hh 256
#define G3 768  // 3*H

typedef _Float16 h2_t __attribute__((ext_vector_type(2)));
typedef _Float16 f16x8 __attribute__((ext_vector_type(8)));
typedef float f32x4 __attribute__((ext_vector_type(4)));
union H2U { unsigned u; _Float16 h[2]; h2_t v; };
union V16 { uint4 u; f16x8 f; };

__device__ __forceinline__ float fdot2f(unsigned a, unsigned b, float c) {
#if __has_builtin(__builtin_amdgcn_fdot2)
    H2U ua, ub; ua.u = a; ub.u = b;
    return __builtin_amdgcn_fdot2(ua.v, ub.v, c, false);
#else
    H2U ua, ub; ua.u = a; ub.u = b;
    return c + (float)ua.h[0] * (float)ub.h[0] + (float)ua.h[1] * (float)ub.h[1];
#endif
}

__device__ __forceinline__ float frcpf(float x) {
#if __has_builtin(__builtin_amdgcn_rcpf)
    return __builtin_amdgcn_rcpf(x);
#else
    return 1.0f / x;
#endif
}
__device__ __forceinline__ float sigmoidf_(float s) { return frcpf(1.0f + __expf(-s)); }
__device__ __forceinline__ float tanhf_(float u) {
    float e = __expf(2.0f * u);
    return 1.0f - 2.0f * frcpf(e + 1.0f);
}
// cross-kg reduction: xor-16 (ds_swizzle BitMode) then xor-32 (__shfl_xor).
// scalar-in/scalar-out (R2 lesson: never pass arrays by pointer).
__device__ __forceinline__ float red4(float v) {
    v += __int_as_float(__builtin_amdgcn_ds_swizzle(__float_as_int(v), 0x401F)); // lane ^= 16
    v += __shfl_xor(v, 32, 64);                                                  // lane ^= 32
    return v;
}
// zero-instruction register-class pin -> AGPR (R7/R8 lesson: builtin MFMA
// for hazard handling; pin only the operand's class).
__device__ __forceinline__ f16x8 agpr_pin(f16x8 v) {
    f16x8 r;
    asm("" : "=a"(r) : "0"(v));
    return r;
}

// ---------------------------------------------------------------------------
// k0: x fp32 -> f16 (into d_out scratch region)
// ---------------------------------------------------------------------------
__global__ void cvt_x_kernel(const float* __restrict__ x, _Float16* __restrict__ xo) {
    const size_t i = ((size_t)blockIdx.x * 256 + threadIdx.x) * 4;
    float4 v = *reinterpret_cast<const float4*>(x + i);
    H2U a, b;
    a.h[0] = (_Float16)v.x; a.h[1] = (_Float16)v.y;
    b.h[0] = (_Float16)v.z; b.h[1] = (_Float16)v.w;
    uint2 o; o.x = a.u; o.y = b.u;
    *reinterpret_cast<uint2*>(xo + i) = o;
}

// ---------------------------------------------------------------------------
// k1: WxT[n][k] f16 from Wx[k][n] fp32  (768 x 256)
// ---------------------------------------------------------------------------
__global__ void wxt_kernel(const float* __restrict__ Wx, _Float16* __restrict__ wxt) {
    const int o = blockIdx.x * 256 + threadIdx.x;  // o = n*128 + kp
    const int n = o >> 7, kp = o & 127;
    float f0 = Wx[(size_t)(2 * kp) * G3 + n];
    float f1 = Wx[(size_t)(2 * kp + 1) * G3 + n];
    H2U u; u.h[0] = (_Float16)f0; u.h[1] = (_Float16)f1;
    reinterpret_cast<unsigned*>(wxt)[o] = u.u;
}

// ---------------------------------------------------------------------------
// k2: xp = A(65536x256,f16) @ WxT^T + bias, f16 out. MFMA 16x16x32_f16.
// (unchanged -- ref-checked)
// ---------------------------------------------------------------------------
__global__ __launch_bounds__(256)
void gemm_xp_kernel(const _Float16* __restrict__ A, const _Float16* __restrict__ Bm,
                    const float* __restrict__ bias, _Float16* __restrict__ xp) {
    __shared__ _Float16 As[128][264];
    __shared__ _Float16 Bs[64][264];
    const int tid = threadIdx.x;
    const int m0 = (blockIdx.x / 12) * 128;
    const int n0 = (blockIdx.x % 12) * 64;

#pragma unroll
    for (int it = 0; it < 16; ++it) {
        int c = tid + it * 256, row = c >> 5, col = c & 31;
        uint4 v = *reinterpret_cast<const uint4*>(A + (size_t)(m0 + row) * 256 + col * 8);
        *reinterpret_cast<uint4*>(&As[row][col * 8]) = v;
    }
#pragma unroll
    for (int it = 0; it < 8; ++it) {
        int c = tid + it * 256, row = c >> 5, col = c & 31;
        uint4 v = *reinterpret_cast<const uint4*>(Bm + (size_t)(n0 + row) * 256 + col * 8);
        *reinterpret_cast<uint4*>(&Bs[row][col * 8]) = v;
    }
    __syncthreads();

    const int wave = tid >> 6, lane = tid & 63;
    const int wr = wave >> 1, wc = wave & 1;
    const int r16 = lane & 15, kg = lane >> 4;

    f32x4 acc[4][2];
#pragma unroll
    for (int mi = 0; mi < 4; ++mi)
#pragma unroll
        for (int ni = 0; ni < 2; ++ni) acc[mi][ni] = (f32x4){0.f, 0.f, 0.f, 0.f};

    float bv[2];
#pragma unroll
    for (int ni = 0; ni < 2; ++ni) bv[ni] = bias[n0 + wc * 32 + ni * 16 + r16];

#pragma unroll
    for (int kk = 0; kk < 8; ++kk) {
        f16x8 a[4], b2[2];
#pragma unroll
        for (int mi = 0; mi < 4; ++mi) {
            V16 t; t.u = *reinterpret_cast<const uint4*>(&As[wr * 64 + mi * 16 + r16][kk * 32 + kg * 8]);
            a[mi] = t.f;
        }
#pragma unroll
        for (int ni = 0; ni < 2; ++ni) {
            V16 t; t.u = *reinterpret_cast<const uint4*>(&Bs[wc * 32 + ni * 16 + r16][kk * 32 + kg * 8]);
            b2[ni] = t.f;
        }
#pragma unroll
        for (int mi = 0; mi < 4; ++mi)
#pragma unroll
            for (int ni = 0; ni < 2; ++ni)
                acc[mi][ni] = __builtin_amdgcn_mfma_f32_16x16x32_f16(a[mi], b2[ni], acc[mi][ni], 0, 0, 0);
    }

#pragma unroll
    for (int mi = 0; mi < 4; ++mi)
#pragma unroll
        for (int ni = 0; ni < 2; ++ni)
#pragma unroll
            for (int r = 0; r < 4; ++r) {
                int row = m0 + wr * 64 + mi * 16 + kg * 4 + r;
                int col = n0 + wc * 32 + ni * 16 + r16;
                xp[(size_t)row * G3 + col] = (_Float16)(acc[mi][ni][r] + bv[ni]);
            }
}

// ---------------------------------------------------------------------------
// k3: GRU scan -- VALU+MFMA hybrid, unified h-read, CROSS-STEP X-PREFETCH.
// 32 blocks x 256 threads (1 wave/SIMD; R5/R8-proven full-256-VGPR regime).
// R9 closed the issue accounting (MFMA at ~80% of its 931-cyc floor; VALU
// ~550 cyc incl. overhead) but left ~1800 cyc/step of stall. Dominant term:
// x-proj loads issued and consumed WITHIN the step -- ~half of xp is served
// from HBM (~900 cyc, FETCH=54MB), and the gate-time vmcnt wait also drains
// the prior y-stores (vmcnt is in-order). Fix: issue x loads for step t+1 at
// the TOP of step t (issue-to-use ~3300 cyc, fully hidden; registers carry
// across the lgkm-only barrier since vmcnt is never drained there).
// af rolling buffer reduced 4->2 to protect the 256-VGPR budget from the 9
// carried x-registers.
// ---------------------------------------------------------------------------
#define DOT6(HU, KP)                                                                  \
    vz0 = fdot2f(w[0][0][KP], HU, vz0); vz1 = fdot2f(w[0][1][KP], HU, vz1);           \
    vr0 = fdot2f(w[1][0][KP], HU, vr0); vr1 = fdot2f(w[1][1][KP], HU, vr1);           \
    vn0 = fdot2f(w[2][0][KP], HU, vn0); vn1 = fdot2f(w[2][1][KP], HU, vn1);

#define GKT(KT, AF)                                                                   \
  {                                                                                   \
    az_a = __builtin_amdgcn_mfma_f32_16x16x32_f16(AF.f, bf[0][0][KT], az_a, 0, 0, 0); \
    DOT6(AF.u.x, 4 * (KT) + 0)                                                        \
    az_b = __builtin_amdgcn_mfma_f32_16x16x32_f16(AF.f, bf[0][1][KT], az_b, 0, 0, 0); \
    DOT6(AF.u.y, 4 * (KT) + 1)                                                        \
    ar_a = __builtin_amdgcn_mfma_f32_16x16x32_f16(AF.f, bf[1][0][KT], ar_a, 0, 0, 0); \
    DOT6(AF.u.z, 4 * (KT) + 2)                                                        \
    ar_b = __builtin_amdgcn_mfma_f32_16x16x32_f16(AF.f, bf[1][1][KT], ar_b, 0, 0, 0); \
    DOT6(AF.u.w, 4 * (KT) + 3)                                                        \
    an_a = __builtin_amdgcn_mfma_f32_16x16x32_f16(AF.f, bf[2][0][KT], an_a, 0, 0, 0); \
    an_b = __builtin_amdgcn_mfma_f32_16x16x32_f16(AF.f, bf[2][1][KT], an_b, 0, 0, 0); \
  }

#define HRD(I) *reinterpret_cast<const uint4*>(hb_ + (I) * 64)

#define GSTEP(PR, PW, T)                                                              \
  {                                                                                   \
    /* prefetch x-proj for step T+1 (consumed NEXT step; ~3300 cyc ahead) */          \
    const int tn_ = ((T) + 1 < Tt) ? (T) + 1 : (T);                                   \
    const _Float16* xtn_ = xq + (size_t)tn_ * G3;                                     \
    const unsigned nxz_ = *reinterpret_cast<const unsigned*>(xtn_);                   \
    const unsigned nxr_ = *reinterpret_cast<const unsigned*>(xtn_ + Hh);              \
    const unsigned nxn_ = *reinterpret_cast<const unsigned*>(xtn_ + 2 * Hh);          \
    const _Float16* xsn_ = xm + (size_t)tn_ * G3;                                     \
    const _Float16 nmz_ = xsn_[0], nmr_ = xsn_[Hh], nmn_ = xsn_[2 * Hh];              \
    f32x4 az_a = {0.f, 0.f, 0.f, 0.f}, az_b = {0.f, 0.f, 0.f, 0.f};                   \
    f32x4 ar_a = {0.f, 0.f, 0.f, 0.f}, ar_b = {0.f, 0.f, 0.f, 0.f};                   \
    f32x4 an_a = {0.f, 0.f, 0.f, 0.f}, an_b = {0.f, 0.f, 0.f, 0.f};                   \
    float vz0 = 0.f, vz1 = 0.f, vr0 = 0.f, vr1 = 0.f, vn0 = 0.f, vn1 = 0.f;           \
    const char* hb_ = reinterpret_cast<const char*>(&hbuf[PR][0]) + kg * 16;          \
    V16 a0, a1;                                                                       \
    a0.u = HRD(0); a1.u = HRD(1);                                                     \
    GKT(0, a0) a0.u = HRD(2);                                                         \
    GKT(1, a1) a1.u = HRD(3);                                                         \
    GKT(2, a0) a0.u = HRD(4);                                                         \
    GKT(3, a1) a1.u = HRD(5);                                                         \
    GKT(4, a0) a0.u = HRD(6);                                                         \
    GKT(5, a1) a1.u = HRD(7);                                                         \
    GKT(6, a0)                                                                        \
    GKT(7, a1)                                                                        \
    /* cross-kg reduce: all lanes end with full-k sums */                             \
    vz0 = red4(vz0); vz1 = red4(vz1);                                                 \
    vr0 = red4(vr0); vr1 = red4(vr1);                                                 \
    vn0 = red4(vn0); vn1 = red4(vn1);                                                 \
    /* MFMA gates first (acc ready right after last MFMA) */                          \
    const float mz = (lane & 16) ? az_b[0] : az_a[0];                                 \
    const float mr = (lane & 16) ? ar_b[0] : ar_a[0];                                 \
    const float mn = (lane & 16) ? an_b[0] : an_a[0];                                 \
    const float zg = sigmoidf_((float)xmz + mz);                                      \
    const float rg = sigmoidf_((float)xmr + mr);                                      \
    const float ng = tanhf_((float)xmn + rg * mn);                                    \
    const float hm = zg * hm_prev + (1.0f - zg) * ng;                                 \
    hm_prev = hm;                                                                     \
    if (lane < 32) {                                                                  \
      reinterpret_cast<_Float16*>(&hbuf[PW][0])[jm] = (_Float16)hm;                   \
      ybm[(size_t)(T) * Hh] = hm;                                                     \
    }                                                                                 \
    /* VALU gates (wave-wide; all kg copies identical after red4) */                  \
    H2U uz, ur, un; uz.u = xzp; ur.u = xrp; un.u = xnp;                               \
    const float z0 = sigmoidf_((float)uz.h[0] + vz0);                                 \
    const float r0 = sigmoidf_((float)ur.h[0] + vr0);                                 \
    const float n0 = tanhf_((float)un.h[0] + r0 * vn0);                               \
    const float hn0 = z0 * hv_prev0 + (1.0f - z0) * n0;                               \
    const float z1 = sigmoidf_((float)uz.h[1] + vz1);                                 \
    const float r1 = sigmoidf_((float)ur.h[1] + vr1);                                 \
    const float n1 = tanhf_((float)un.h[1] + r1 * vn1);                               \
    const float hn1 = z1 * hv_prev1 + (1.0f - z1) * n1;                               \
    hv_prev0 = hn0; hv_prev1 = hn1;                                                   \
    if (lane < 16) {                                                                  \
      H2U hp; hp.h[0] = (_Float16)hn0; hp.h[1] = (_Float16)hn1;                       \
      hbuf[PW][16 * wv + s16] = hp.u;                                                 \
      float2 yv; yv.x = hn0; yv.y = hn1;                                              \
      *reinterpret_cast<float2*>(ybv + (size_t)(T) * Hh) = yv;                        \
    }                                                                                 \
    /* rotate the x carry */                                                          \
    xzp = nxz_; xrp = nxr_; xnp = nxn_;                                               \
    xmz = nmz_; xmr = nmr_; xmn = nmn_;                                               \
    __builtin_amdgcn_sched_barrier(0);                                                \
    asm volatile("s_waitcnt lgkmcnt(0)" ::: "memory");                                \
    __builtin_amdgcn_s_barrier();                                                     \
    __builtin_amdgcn_sched_barrier(0);                                                \
  }

__global__ __launch_bounds__(256)
__attribute__((amdgpu_waves_per_eu(1, 1)))
void gru_scan_kernel(const _Float16* __restrict__ xp, const float* __restrict__ Wh,
                     float* __restrict__ y) {
    __shared__ unsigned hbuf[2][128];  // 2 x 256 f16, linear (broadcast reads: 0 conflicts)

    const int tid = threadIdx.x;
    const int b = blockIdx.x;
    const int wv = tid >> 6, lane = tid & 63;
    const int s16 = lane & 15, kg = lane >> 4;

    // --- VALU weights: cols {32wv+2s16, +1} x 3 gates, k-set == A-frag set:
    //     k = 32*kt + 8*kg + 2*i + {0,1}  -> w[g][c][4*kt+i]  (192 u32) ---
    unsigned w[3][2][32];
#pragma unroll
    for (int g = 0; g < 3; ++g) {
        const int c0 = g * Hh + 32 * wv + 2 * s16;
#pragma unroll
        for (int kt = 0; kt < 8; ++kt)
#pragma unroll
            for (int i = 0; i < 4; ++i) {
                const int k = 32 * kt + 8 * kg + 2 * i;
                float2 f0 = *reinterpret_cast<const float2*>(Wh + (size_t)k * G3 + c0);
                float2 f1 = *reinterpret_cast<const float2*>(Wh + (size_t)(k + 1) * G3 + c0);
                H2U p0, p1;
                p0.h[0] = (_Float16)f0.x; p0.h[1] = (_Float16)f1.x;
                p1.h[0] = (_Float16)f0.y; p1.h[1] = (_Float16)f1.y;
                w[g][0][4 * kt + i] = p0.u;
                w[g][1][4 * kt + i] = p1.u;
            }
    }

    // --- MFMA B-fragments (AGPR-pinned): col = g*256 + 128+32wv+16w2+(lane&15),
    //     k = 32kt + 8kg + j ---
    f16x8 bf[3][2][8];
#pragma unroll
    for (int g = 0; g < 3; ++g)
#pragma unroll
        for (int w2 = 0; w2 < 2; ++w2)
#pragma unroll
            for (int kt = 0; kt < 8; ++kt) {
                V16 t;
#pragma unroll
                for (int j = 0; j < 8; ++j) {
                    const int k = 32 * kt + 8 * kg + j;
                    t.f[j] = (_Float16)Wh[(size_t)k * G3 + g * Hh + 128 + 32 * wv + 16 * w2 + s16];
                }
                bf[g][w2][kt] = agpr_pin(t.f);
            }

    if (tid < 128) hbuf[0][tid] = 0u;  // h0 = 0
    float hv_prev0 = 0.f, hv_prev1 = 0.f, hm_prev = 0.f;

    const int jv = 32 * wv + 2 * s16;            // VALU col pair base
    const int jm = 128 + 32 * wv + (lane & 31);  // MFMA col (lanes < 32 store)
    const _Float16* xq = xp + (size_t)b * Tt * G3 + jv;
    const _Float16* xm = xp + (size_t)b * Tt * G3 + jm;
    float* ybv = y + (size_t)b * Tt * Hh + jv;
    float* ybm = y + (size_t)b * Tt * Hh + jm;

    // prime the x carry for t = 0
    unsigned xzp = *reinterpret_cast<const unsigned*>(xq);
    unsigned xrp = *reinterpret_cast<const unsigned*>(xq + Hh);
    unsigned xnp = *reinterpret_cast<const unsigned*>(xq + 2 * Hh);
    _Float16 xmz = xm[0], xmr = xm[Hh], xmn = xm[2 * Hh];

    __syncthreads();  // one-time full barrier (drains weight loads too)

#pragma unroll 1
    for (int t = 0; t < Tt; t += 2) {
        GSTEP(0, 1, t);
        GSTEP(1, 0, t + 1);
    }
}

extern "C" void kernel_launch(void* const* d_in, const int* in_sizes, int n_in,
                              void* d_out, int out_size, void* d_ws, size_t ws_size,
                              hipStream_t stream) {
    (void)in_sizes; (void)n_in; (void)out_size; (void)ws_size;
    const float* x    = (const float*)d_in[0];
    const float* Wx   = (const float*)d_in[1];
    const float* Wh   = (const float*)d_in[2];
    const float* bias = (const float*)d_in[3];
    float* y = (float*)d_out;

    _Float16* xp   = (_Float16*)d_ws;                                // 96 MB
    _Float16* xf16 = (_Float16*)d_out;                               // 33.5 MB scratch in d_out
    _Float16* wxt  = (_Float16*)((char*)d_out + (size_t)33554432);   // 384 KB, after xf16

    cvt_x_kernel<<<dim3(16384), dim3(256), 0, stream>>>(x, xf16);
    wxt_kernel<<<dim3(384), dim3(256), 0, stream>>>(Wx, wxt);
    gemm_xp_kernel<<<dim3(6144), dim3(256), 0, stream>>>(xf16, wxt, bias, xp);
    // scan reads only ws, writes all of d_out (overwriting the scratch regions)
    gru_scan_kernel<<<dim3(Bb), dim3(256), 0, stream>>>(xp, Wh, y);
}

// Round 11
// 2418.308 us; speedup vs baseline: 1.5012x; 1.1276x over previous
//
#include <hip/hip_runtime.h>

#define Bb 32
#define Tt 2048
#define Dd 256
#define Hh 256
#define G3 768  // 3*H

typedef _Float16 h2_t __attribute__((ext_vector_type(2)));
typedef _Float16 f16x8 __attribute__((ext_vector_type(8)));
typedef float f32x4 __attribute__((ext_vector_type(4)));
union H2U { unsigned u; _Float16 h[2]; h2_t v; };
union V16 { uint4 u; f16x8 f; };

__device__ __forceinline__ float frcpf(float x) {
#if __has_builtin(__builtin_amdgcn_rcpf)
    return __builtin_amdgcn_rcpf(x);
#else
    return 1.0f / x;
#endif
}
__device__ __forceinline__ float sigmoidf_(float s) { return frcpf(1.0f + __expf(-s)); }
__device__ __forceinline__ float tanhf_(float u) {
    float e = __expf(2.0f * u);
    return 1.0f - 2.0f * frcpf(e + 1.0f);
}
// zero-instruction register-class pin -> AGPR (R7/R8 lesson: builtin MFMA
// for hazard handling; pin only the operand's class).
__device__ __forceinline__ f16x8 agpr_pin(f16x8 v) {
    f16x8 r;
    asm("" : "=a"(r) : "0"(v));
    return r;
}

// ---------------------------------------------------------------------------
// k0: x fp32 -> f16 (into d_out scratch region)
// ---------------------------------------------------------------------------
__global__ void cvt_x_kernel(const float* __restrict__ x, _Float16* __restrict__ xo) {
    const size_t i = ((size_t)blockIdx.x * 256 + threadIdx.x) * 4;
    float4 v = *reinterpret_cast<const float4*>(x + i);
    H2U a, b;
    a.h[0] = (_Float16)v.x; a.h[1] = (_Float16)v.y;
    b.h[0] = (_Float16)v.z; b.h[1] = (_Float16)v.w;
    uint2 o; o.x = a.u; o.y = b.u;
    *reinterpret_cast<uint2*>(xo + i) = o;
}

// ---------------------------------------------------------------------------
// k1: WxT[n][k] f16 from Wx[k][n] fp32  (768 x 256)
// ---------------------------------------------------------------------------
__global__ void wxt_kernel(const float* __restrict__ Wx, _Float16* __restrict__ wxt) {
    const int o = blockIdx.x * 256 + threadIdx.x;  // o = n*128 + kp
    const int n = o >> 7, kp = o & 127;
    float f0 = Wx[(size_t)(2 * kp) * G3 + n];
    float f1 = Wx[(size_t)(2 * kp + 1) * G3 + n];
    H2U u; u.h[0] = (_Float16)f0; u.h[1] = (_Float16)f1;
    reinterpret_cast<unsigned*>(wxt)[o] = u.u;
}

// ---------------------------------------------------------------------------
// k2: xp = A(65536x256,f16) @ WxT^T + bias, f16 out. MFMA 16x16x32_f16.
// (unchanged -- ref-checked)
// ---------------------------------------------------------------------------
__global__ __launch_bounds__(256)
void gemm_xp_kernel(const _Float16* __restrict__ A, const _Float16* __restrict__ Bm,
                    const float* __restrict__ bias, _Float16* __restrict__ xp) {
    __shared__ _Float16 As[128][264];
    __shared__ _Float16 Bs[64][264];
    const int tid = threadIdx.x;
    const int m0 = (blockIdx.x / 12) * 128;
    const int n0 = (blockIdx.x % 12) * 64;

#pragma unroll
    for (int it = 0; it < 16; ++it) {
        int c = tid + it * 256, row = c >> 5, col = c & 31;
        uint4 v = *reinterpret_cast<const uint4*>(A + (size_t)(m0 + row) * 256 + col * 8);
        *reinterpret_cast<uint4*>(&As[row][col * 8]) = v;
    }
#pragma unroll
    for (int it = 0; it < 8; ++it) {
        int c = tid + it * 256, row = c >> 5, col = c & 31;
        uint4 v = *reinterpret_cast<const uint4*>(Bm + (size_t)(n0 + row) * 256 + col * 8);
        *reinterpret_cast<uint4*>(&Bs[row][col * 8]) = v;
    }
    __syncthreads();

    const int wave = tid >> 6, lane = tid & 63;
    const int wr = wave >> 1, wc = wave & 1;
    const int r16 = lane & 15, kg = lane >> 4;

    f32x4 acc[4][2];
#pragma unroll
    for (int mi = 0; mi < 4; ++mi)
#pragma unroll
        for (int ni = 0; ni < 2; ++ni) acc[mi][ni] = (f32x4){0.f, 0.f, 0.f, 0.f};

    float bv[2];
#pragma unroll
    for (int ni = 0; ni < 2; ++ni) bv[ni] = bias[n0 + wc * 32 + ni * 16 + r16];

#pragma unroll
    for (int kk = 0; kk < 8; ++kk) {
        f16x8 a[4], b2[2];
#pragma unroll
        for (int mi = 0; mi < 4; ++mi) {
            V16 t; t.u = *reinterpret_cast<const uint4*>(&As[wr * 64 + mi * 16 + r16][kk * 32 + kg * 8]);
            a[mi] = t.f;
        }
#pragma unroll
        for (int ni = 0; ni < 2; ++ni) {
            V16 t; t.u = *reinterpret_cast<const uint4*>(&Bs[wc * 32 + ni * 16 + r16][kk * 32 + kg * 8]);
            b2[ni] = t.f;
        }
#pragma unroll
        for (int mi = 0; mi < 4; ++mi)
#pragma unroll
            for (int ni = 0; ni < 2; ++ni)
                acc[mi][ni] = __builtin_amdgcn_mfma_f32_16x16x32_f16(a[mi], b2[ni], acc[mi][ni], 0, 0, 0);
    }

#pragma unroll
    for (int mi = 0; mi < 4; ++mi)
#pragma unroll
        for (int ni = 0; ni < 2; ++ni)
#pragma unroll
            for (int r = 0; r < 4; ++r) {
                int row = m0 + wr * 64 + mi * 16 + kg * 4 + r;
                int col = n0 + wc * 32 + ni * 16 + r16;
                xp[(size_t)row * G3 + col] = (_Float16)(acc[mi][ni][r] + bv[ni]);
            }
}

// ---------------------------------------------------------------------------
// k3: GRU scan -- ALL-MFMA, 2 waves/SIMD (the R3 structure with its two
// defects fixed). 32 blocks x 512 threads (8 waves).
//
// WHY (R3..R10 evidence): the 1-wave/SIMD hybrid has a 931-cyc floor but
// realizes 3100 (latency-bound, nothing fills stalls; TLP impossible at its
// 472-reg/wave demand). R3 (all-MFMA, 2 waves/SIMD) remains the best scan
// measured (2496 cyc/step vs 1863 floor) BECAUSE the second wave fills
// stalls. Its 630-cyc overhead had two identified causes, both fixed here:
//   1. streamed-weight reads at 80B stride -> 25M bank conflicts. Now R6's
//      verified wave-linear [wave][tile][lane] uint4 layout (0 conflicts).
//   2. weight regs exceeded the 2-wave class budget -> parking moves. Now
//      budgeted exactly: per wave = 168 AGPR (K-frags 0..6 agpr_pin'd)
//      + 24 AGPR acc + ~60 VGPR working = 252 <= 256 (512-reg SIMD pool).
// Per wave: h-cols [32wv,+32) x 3 gates = 6 tiles (3g x 2 sub-windows) x
// 8 K-frags = 48 MFMA; A = h broadcast from LDS (rows identical, acc[0]
// holds the 16 cols -- R3/R9/R10-proven). Per SIMD: 96 MFMA -> 1863 cyc
// floor. DS: 15 b128/wave/step = 120/CU ~ 1440 cyc < floor. x loads
// in-step (issue-to-use ~1700 cyc, hidden). Gates fp32, hm_prev carries.
// ---------------------------------------------------------------------------
#define GKT7(KT, AF)                                                                   \
    az_a = __builtin_amdgcn_mfma_f32_16x16x32_f16(AF.f, bf[0][0][KT], az_a, 0, 0, 0);  \
    az_b = __builtin_amdgcn_mfma_f32_16x16x32_f16(AF.f, bf[0][1][KT], az_b, 0, 0, 0);  \
    ar_a = __builtin_amdgcn_mfma_f32_16x16x32_f16(AF.f, bf[1][0][KT], ar_a, 0, 0, 0);  \
    ar_b = __builtin_amdgcn_mfma_f32_16x16x32_f16(AF.f, bf[1][1][KT], ar_b, 0, 0, 0);  \
    an_a = __builtin_amdgcn_mfma_f32_16x16x32_f16(AF.f, bf[2][0][KT], an_a, 0, 0, 0);  \
    an_b = __builtin_amdgcn_mfma_f32_16x16x32_f16(AF.f, bf[2][1][KT], an_b, 0, 0, 0);

#define GKTS(AF)                                                                       \
    az_a = __builtin_amdgcn_mfma_f32_16x16x32_f16(AF.f, s0.f, az_a, 0, 0, 0);          \
    az_b = __builtin_amdgcn_mfma_f32_16x16x32_f16(AF.f, s1.f, az_b, 0, 0, 0);          \
    ar_a = __builtin_amdgcn_mfma_f32_16x16x32_f16(AF.f, s2.f, ar_a, 0, 0, 0);          \
    ar_b = __builtin_amdgcn_mfma_f32_16x16x32_f16(AF.f, s3.f, ar_b, 0, 0, 0);          \
    an_a = __builtin_amdgcn_mfma_f32_16x16x32_f16(AF.f, s4.f, an_a, 0, 0, 0);          \
    an_b = __builtin_amdgcn_mfma_f32_16x16x32_f16(AF.f, s5.f, an_b, 0, 0, 0);

#define HRD(I) *reinterpret_cast<const uint4*>(hb_ + (I) * 64)

#define GSTEP(PR, PW, T)                                                              \
  {                                                                                   \
    /* x loads for THIS step (vmem; consumed at gates ~1700 cyc later) */             \
    const _Float16* xt_ = xm + (size_t)(T) * G3;                                      \
    const _Float16 xgz = xt_[0], xgr = xt_[Hh], xgn = xt_[2 * Hh];                    \
    /* streamed K-frag 7 (LDS, wave-linear layout; laundered offset keeps */          \
    /* the reads inside the loop instead of hoisted into registers) */                \
    unsigned off_ = 0;                                                                \
    asm volatile("" : "+v"(off_));                                                    \
    const uint4* swp_ = wlds4 + (wv * 6) * 64 + lane + off_;                          \
    V16 s0, s1, s2, s3, s4, s5;                                                       \
    s0.u = swp_[0];   s1.u = swp_[64];  s2.u = swp_[128];                             \
    s3.u = swp_[192]; s4.u = swp_[256]; s5.u = swp_[320];                             \
    f32x4 az_a = {0.f, 0.f, 0.f, 0.f}, az_b = {0.f, 0.f, 0.f, 0.f};                   \
    f32x4 ar_a = {0.f, 0.f, 0.f, 0.f}, ar_b = {0.f, 0.f, 0.f, 0.f};                   \
    f32x4 an_a = {0.f, 0.f, 0.f, 0.f}, an_b = {0.f, 0.f, 0.f, 0.f};                   \
    const char* hb_ = reinterpret_cast<const char*>(&hbuf[PR][0]) + kg * 16;          \
    V16 a0, a1;                                                                       \
    a0.u = HRD(0); a1.u = HRD(1);                                                     \
    GKT7(0, a0) a0.u = HRD(2);                                                        \
    GKT7(1, a1) a1.u = HRD(3);                                                        \
    GKT7(2, a0) a0.u = HRD(4);                                                        \
    GKT7(3, a1) a1.u = HRD(5);                                                        \
    GKT7(4, a0) a0.u = HRD(6);                                                        \
    GKT7(5, a1) a1.u = HRD(7);                                                        \
    GKT7(6, a0)                                                                       \
    GKTS(a1)                                                                          \
    /* extract (rows identical -> acc[0]); sub-window by lane bit 4 */                \
    const float mz = (lane & 16) ? az_b[0] : az_a[0];                                 \
    const float mr = (lane & 16) ? ar_b[0] : ar_a[0];                                 \
    const float mn = (lane & 16) ? an_b[0] : an_a[0];                                 \
    const float zg = sigmoidf_((float)xgz + mz);                                      \
    const float rg = sigmoidf_((float)xgr + mr);                                      \
    const float ng = tanhf_((float)xgn + rg * mn);                                    \
    const float hm = zg * hm_prev + (1.0f - zg) * ng;                                 \
    hm_prev = hm;                                                                     \
    if (lane < 32) {                                                                  \
      reinterpret_cast<_Float16*>(&hbuf[PW][0])[jm] = (_Float16)hm;                   \
      ybm[(size_t)(T) * Hh] = hm;                                                     \
    }                                                                                 \
    __builtin_amdgcn_sched_barrier(0);                                                \
    asm volatile("s_waitcnt lgkmcnt(0)" ::: "memory");                                \
    __builtin_amdgcn_s_barrier();                                                     \
    __builtin_amdgcn_sched_barrier(0);                                                \
  }

__global__ __launch_bounds__(512)
__attribute__((amdgpu_waves_per_eu(2, 2)))
void gru_scan_kernel(const _Float16* __restrict__ xp, const float* __restrict__ Wh,
                     float* __restrict__ y) {
    __shared__ uint4 wlds4[8 * 6 * 64];   // 48 KB: K-frag 7, [wave][g*2+sub][lane]
    __shared__ unsigned hbuf[2][128];     // 2 x 256 f16, linear (broadcast reads)

    const int tid = threadIdx.x;
    const int b = blockIdx.x;
    const int wv = tid >> 6, lane = tid & 63;
    const int s16 = lane & 15, kg = lane >> 4;

    // --- B-fragments: col = g*256 + 32wv + 16*w2 + s16, k = 32kt + 8kg + j.
    //     K-frags 0..6 -> AGPR (agpr_pin, 168 regs); K-frag 7 -> LDS. ---
    f16x8 bf[3][2][7];
#pragma unroll
    for (int g = 0; g < 3; ++g)
#pragma unroll
        for (int w2 = 0; w2 < 2; ++w2) {
#pragma unroll
            for (int kt = 0; kt < 7; ++kt) {
                V16 t;
#pragma unroll
                for (int j = 0; j < 8; ++j) {
                    const int k = 32 * kt + 8 * kg + j;
                    t.f[j] = (_Float16)Wh[(size_t)k * G3 + g * Hh + 32 * wv + 16 * w2 + s16];
                }
                bf[g][w2][kt] = agpr_pin(t.f);
            }
            V16 t7;
#pragma unroll
            for (int j = 0; j < 8; ++j) {
                const int k = 224 + 8 * kg + j;
                t7.f[j] = (_Float16)Wh[(size_t)k * G3 + g * Hh + 32 * wv + 16 * w2 + s16];
            }
            wlds4[(wv * 6 + g * 2 + w2) * 64 + lane] = t7.u;
        }

    if (tid < 128) hbuf[0][tid] = 0u;  // h0 = 0
    float hm_prev = 0.f;

    const int jm = 32 * wv + (lane & 31);  // this lane's h-col (lanes 32-63 duplicate)
    const _Float16* xm = xp + (size_t)b * Tt * G3 + jm;
    float* ybm = y + (size_t)b * Tt * Hh + jm;

    __syncthreads();  // one-time full barrier (drains weight loads + LDS stores)

#pragma unroll 1
    for (int t = 0; t < Tt; t += 2) {
        GSTEP(0, 1, t);
        GSTEP(1, 0, t + 1);
    }
}

extern "C" void kernel_launch(void* const* d_in, const int* in_sizes, int n_in,
                              void* d_out, int out_size, void* d_ws, size_t ws_size,
                              hipStream_t stream) {
    (void)in_sizes; (void)n_in; (void)out_size; (void)ws_size;
    const float* x    = (const float*)d_in[0];
    const float* Wx   = (const float*)d_in[1];
    const float* Wh   = (const float*)d_in[2];
    const float* bias = (const float*)d_in[3];
    float* y = (float*)d_out;

    _Float16* xp   = (_Float16*)d_ws;                                // 96 MB
    _Float16* xf16 = (_Float16*)d_out;                               // 33.5 MB scratch in d_out
    _Float16* wxt  = (_Float16*)((char*)d_out + (size_t)33554432);   // 384 KB, after xf16

    cvt_x_kernel<<<dim3(16384), dim3(256), 0, stream>>>(x, xf16);
    wxt_kernel<<<dim3(384), dim3(256), 0, stream>>>(Wx, wxt);
    gemm_xp_kernel<<<dim3(6144), dim3(256), 0, stream>>>(xf16, wxt, bias, xp);
    // scan reads only ws, writes all of d_out (overwriting the scratch regions)
    gru_scan_kernel<<<dim3(Bb), dim3(512), 0, stream>>>(xp, Wh, y);
}